// Round 9
// baseline (38.759 us; speedup 1.0000x reference)
//
#include <hip/hip_runtime.h>

// ContinuityLoss: loss = 0.01/(n(n-1)) * sum_{i!=j} exp(-|pi-pj|^2/2) * |oi-oj|
// points: [N,2] f32, outputs: [N,8] f32, scalar f32 out. N = 8192.
//
// R7 (resubmitted R8 after infra failure): eliminate the CU-shared LDS pipe
// from the inner loop (R5 was LDS-issue bound: 5 ds_read/j/wave x 17 waves/CU
// serialized on one LDS unit).
//  - j-chunk (64 cols = wave size) lives in 10 VGPRs per lane (1 lane = 1 col)
//  - per j: broadcast via v_readlane (VALU, per-SIMD, 4x parallel per CU)
//  - MROW=4 rows/thread (BLK=128): readlanes amortize over 4 rows; 4
//    independent row chains give ILP at 2.1 waves/SIMD (no memory in loop)
//  - triangular super-tiles: 16 panels of 512 -> 136 tiles x 8 chunks = 1088
//    blocks; off-diagonal tiles weighted x2
//  - packed f32 math, exp2 with folded -0.5*log2(e), raw v_sqrt_f32
//  - fp32 thread partials -> fp64 block partials -> deterministic final reduce

typedef float v2f __attribute__((ext_vector_type(2)));

constexpr int BLK    = 128;                 // threads per block (2 waves)
constexpr int MROW   = 4;                   // rows per thread
constexpr int PANEL  = BLK * MROW;          // 512 rows per panel
constexpr int K      = 8192 / PANEL;        // 16 panels
constexpr int NTILES = K * (K + 1) / 2;     // 136 upper-tri super-tiles
constexpr int CHUNK  = 64;                  // columns per block (= wave size)
constexpr int NCHUNK = PANEL / CHUNK;       // 8 chunks per super-tile
constexpr int NBLOCKS = NTILES * NCHUNK;    // 1088 blocks

__device__ __forceinline__ float rl(float v, int j) {
    return __int_as_float(__builtin_amdgcn_readlane(__float_as_int(v), j));
}

__global__ __launch_bounds__(BLK) void cont_pairs(
    const float* __restrict__ points, const float* __restrict__ outputs,
    double* __restrict__ partials)
{
    const int b     = blockIdx.x;
    const int tile  = b >> 3;               // which (r,s) super-tile
    const int chunk = b & (NCHUNK - 1);     // which 64-col chunk within it

    // decode tile -> upper-triangular (r, s), r <= s  (uniform, <=16 iters)
    int r = 0, base = 0;
    while (tile >= base + (K - r)) { base += K - r; ++r; }
    const int s = r + (tile - base);

    const int jbase = s * PANEL + chunk * CHUNK;
    const int lane  = threadIdx.x & 63;

    // j-side: each lane of each wave holds one column in registers
    v2f pjv, ojv[4];
    {
        const int j = jbase + lane;
        pjv = reinterpret_cast<const v2f*>(points)[j];
        const v2f* o = reinterpret_cast<const v2f*>(outputs + 8 * j);
        ojv[0] = o[0]; ojv[1] = o[1]; ojv[2] = o[2]; ojv[3] = o[3];
    }

    // i-side: MROW rows per thread (coalesced: rows k*BLK apart)
    v2f pi[MROW], oi[MROW][4];
    const int ibase = r * PANEL + threadIdx.x;
    #pragma unroll
    for (int k = 0; k < MROW; ++k) {
        const int i = ibase + k * BLK;
        pi[k] = reinterpret_cast<const v2f*>(points)[i];
        const v2f* o = reinterpret_cast<const v2f*>(outputs + 8 * i);
        oi[k][0] = o[0]; oi[k][1] = o[1]; oi[k][2] = o[2]; oi[k][3] = o[3];
    }

    constexpr float kE = -0.72134752044f;   // -0.5 * log2(e)
    float acc[MROW] = {0.f, 0.f, 0.f, 0.f};

    #pragma unroll 4
    for (int j = 0; j < CHUNK; ++j) {
        // broadcast column j from lane j's registers (uniform -> SGPRs)
        v2f pj, a0, a1, a2, a3;
        pj.x = rl(pjv.x, j);    pj.y = rl(pjv.y, j);
        a0.x = rl(ojv[0].x, j); a0.y = rl(ojv[0].y, j);
        a1.x = rl(ojv[1].x, j); a1.y = rl(ojv[1].y, j);
        a2.x = rl(ojv[2].x, j); a2.y = rl(ojv[2].y, j);
        a3.x = rl(ojv[3].x, j); a3.y = rl(ojv[3].y, j);
        #pragma unroll
        for (int k = 0; k < MROW; ++k) {
            v2f dp = pi[k] - pj;
            float d2 = dp.x * dp.x + dp.y * dp.y;
            float w  = __builtin_amdgcn_exp2f(d2 * kE);
            v2f t0 = oi[k][0] - a0;
            v2f t1 = oi[k][1] - a1;
            v2f t2 = oi[k][2] - a2;
            v2f t3 = oi[k][3] - a3;
            v2f q  = t0 * t0;
            q += t1 * t1;
            q += t2 * t2;
            q += t3 * t3;
            // i==j contributes exactly 0 (q==0) -> no diagonal mask needed
            acc[k] += w * __builtin_amdgcn_sqrtf(q.x + q.y);
        }
    }

    float sum = (acc[0] + acc[1]) + (acc[2] + acc[3]);
    #pragma unroll
    for (int off = 32; off > 0; off >>= 1)
        sum += __shfl_down(sum, off, 64);

    __shared__ float wpart[BLK / 64];
    if ((threadIdx.x & 63) == 0) wpart[threadIdx.x >> 6] = sum;
    __syncthreads();
    if (threadIdx.x == 0) {
        double d = 0.0;
        #pragma unroll
        for (int w = 0; w < BLK / 64; ++w) d += (double)wpart[w];
        partials[b] = (r < s) ? 2.0 * d : d;   // off-diagonal tiles count twice
    }
}

__global__ __launch_bounds__(1024) void cont_final(
    const double* __restrict__ partials, int nparts,
    float* __restrict__ out, double scale)
{
    const int tid = threadIdx.x;
    double sum = 0.0;
    for (int i = tid; i < nparts; i += 1024) sum += partials[i];
    #pragma unroll
    for (int off = 32; off > 0; off >>= 1)
        sum += __shfl_down(sum, off, 64);

    __shared__ double ws[1024 / 64];
    if ((tid & 63) == 0) ws[tid >> 6] = sum;
    __syncthreads();
    if (tid == 0) {
        double t = 0.0;
        #pragma unroll
        for (int w = 0; w < 1024 / 64; ++w) t += ws[w];
        out[0] = (float)(t * scale);
    }
}

extern "C" void kernel_launch(void* const* d_in, const int* in_sizes, int n_in,
                              void* d_out, int out_size, void* d_ws, size_t ws_size,
                              hipStream_t stream) {
    const float* points  = (const float*)d_in[0];
    const float* outputs = (const float*)d_in[1];
    float* out = (float*)d_out;

    const int n = in_sizes[0] / 2;             // 8192
    double* partials = (double*)d_ws;          // 1088 * 8B = 8704 B scratch

    cont_pairs<<<dim3(NBLOCKS), dim3(BLK), 0, stream>>>(points, outputs, partials);

    const double scale = 0.01 / ((double)n * (double)(n - 1));
    cont_final<<<1, 1024, 0, stream>>>(partials, NBLOCKS, out, scale);
}

// Round 10
// 35.880 us; speedup vs baseline: 1.0802x; 1.0802x over previous
//
#include <hip/hip_runtime.h>

// ContinuityLoss: loss = 0.01/(n(n-1)) * sum_{i!=j} exp(-|pi-pj|^2/2) * |oi-oj|
// points: [N,2] f32, outputs: [N,8] f32, scalar f32 out. N = 8192.
//
// R9: R5 structure (LDS broadcast, measured 29.4us) with the LDS-pipe load cut:
//  - R5 was LDS-issue bound: 5 ds_read_b64 per j per wave, 17 waves/CU ->
//    LDS demand ~2x VALU demand -> VALUBusy ~38%. (R7's readlane alternative
//    regressed: broadcast moved onto the VALU pipe itself.)
//  - pack j-data as float4+float4+float2 -> 3 ds_reads/j (~18 cyc vs 30)
//  - MROW=4 (BLK=256, PANEL=1024): each broadcast feeds 4 rows -> LDS:VALU
//    demand ratio down 3.3x vs R5 -> VALU-bound
//  - CHUNK=32 -> 36 tiles x 32 chunks = 1152 blocks (18 waves/CU, 4.5/SIMD)
//  - triangular symmetry: off-diagonal super-tiles weighted x2
//  - packed f32 math, exp2 with folded -0.5*log2(e), raw v_sqrt_f32
//  - fp32 thread partials -> fp64 block partials -> deterministic final reduce

typedef float v2f __attribute__((ext_vector_type(2)));
typedef float v4f __attribute__((ext_vector_type(4)));

constexpr int BLK    = 256;                 // threads per block (4 waves)
constexpr int MROW   = 4;                   // rows per thread
constexpr int PANEL  = BLK * MROW;          // 1024 rows per panel
constexpr int K      = 8192 / PANEL;        // 8 panels
constexpr int NTILES = K * (K + 1) / 2;     // 36 upper-tri super-tiles
constexpr int CHUNK  = 32;                  // columns per block
constexpr int NCHUNK = PANEL / CHUNK;       // 32 chunks per super-tile
constexpr int NBLOCKS = NTILES * NCHUNK;    // 1152 blocks

__global__ __launch_bounds__(BLK) void cont_pairs(
    const float* __restrict__ points, const float* __restrict__ outputs,
    double* __restrict__ partials)
{
    const int b     = blockIdx.x;
    const int tile  = b / NCHUNK;           // which (r,s) super-tile
    const int chunk = b & (NCHUNK - 1);     // which 32-col chunk within it

    // decode tile -> upper-triangular (r, s), r <= s  (uniform, <=8 iters)
    int r = 0, base = 0;
    while (tile >= base + (K - r)) { base += K - r; ++r; }
    const int s = r + (tile - base);

    const int jbase = s * PANEL + chunk * CHUNK;

    __shared__ v4f soA[CHUNK];              // outputs[j][0:4]
    __shared__ v4f soB[CHUNK];              // outputs[j][4:8]
    __shared__ v2f sp[CHUNK];               // points[j]

    if (threadIdx.x < CHUNK) {
        const int j = jbase + threadIdx.x;
        const v4f* o = reinterpret_cast<const v4f*>(outputs + 8 * j);
        soA[threadIdx.x] = o[0];
        soB[threadIdx.x] = o[1];
        sp[threadIdx.x]  = reinterpret_cast<const v2f*>(points)[j];
    }

    // i-side: MROW rows per thread (coalesced: rows k*BLK apart)
    v2f pi[MROW];
    v4f oiA[MROW], oiB[MROW];
    const int ibase = r * PANEL + threadIdx.x;
    #pragma unroll
    for (int k = 0; k < MROW; ++k) {
        const int i = ibase + k * BLK;
        pi[k] = reinterpret_cast<const v2f*>(points)[i];
        const v4f* o = reinterpret_cast<const v4f*>(outputs + 8 * i);
        oiA[k] = o[0];
        oiB[k] = o[1];
    }
    __syncthreads();

    constexpr float kE = -0.72134752044f;   // -0.5 * log2(e)
    float acc[MROW] = {0.f, 0.f, 0.f, 0.f};

    #pragma unroll 4
    for (int j = 0; j < CHUNK; ++j) {
        const v2f pj = sp[j];               // 1x ds_read_b64  (broadcast)
        const v4f a  = soA[j];              // 1x ds_read_b128 (broadcast)
        const v4f c  = soB[j];              // 1x ds_read_b128 (broadcast)
        #pragma unroll
        for (int k = 0; k < MROW; ++k) {
            v2f dp = pi[k] - pj;
            float d2 = dp.x * dp.x + dp.y * dp.y;
            float w  = __builtin_amdgcn_exp2f(d2 * kE);
            v4f t0 = oiA[k] - a;
            v4f t1 = oiB[k] - c;
            v4f q  = t0 * t0;
            q += t1 * t1;
            float dd = (q.x + q.y) + (q.z + q.w);
            // i==j contributes exactly 0 (dd==0) -> no diagonal mask needed
            acc[k] += w * __builtin_amdgcn_sqrtf(dd);
        }
    }

    float sum = (acc[0] + acc[1]) + (acc[2] + acc[3]);
    #pragma unroll
    for (int off = 32; off > 0; off >>= 1)
        sum += __shfl_down(sum, off, 64);

    __shared__ float wpart[BLK / 64];
    if ((threadIdx.x & 63) == 0) wpart[threadIdx.x >> 6] = sum;
    __syncthreads();
    if (threadIdx.x == 0) {
        double d = 0.0;
        #pragma unroll
        for (int w = 0; w < BLK / 64; ++w) d += (double)wpart[w];
        partials[b] = (r < s) ? 2.0 * d : d;   // off-diagonal tiles count twice
    }
}

__global__ __launch_bounds__(1024) void cont_final(
    const double* __restrict__ partials, int nparts,
    float* __restrict__ out, double scale)
{
    const int tid = threadIdx.x;
    double sum = 0.0;
    for (int i = tid; i < nparts; i += 1024) sum += partials[i];
    #pragma unroll
    for (int off = 32; off > 0; off >>= 1)
        sum += __shfl_down(sum, off, 64);

    __shared__ double ws[1024 / 64];
    if ((tid & 63) == 0) ws[tid >> 6] = sum;
    __syncthreads();
    if (tid == 0) {
        double t = 0.0;
        #pragma unroll
        for (int w = 0; w < 1024 / 64; ++w) t += ws[w];
        out[0] = (float)(t * scale);
    }
}

extern "C" void kernel_launch(void* const* d_in, const int* in_sizes, int n_in,
                              void* d_out, int out_size, void* d_ws, size_t ws_size,
                              hipStream_t stream) {
    const float* points  = (const float*)d_in[0];
    const float* outputs = (const float*)d_in[1];
    float* out = (float*)d_out;

    const int n = in_sizes[0] / 2;             // 8192
    double* partials = (double*)d_ws;          // 1152 * 8B = 9216 B scratch

    cont_pairs<<<dim3(NBLOCKS), dim3(BLK), 0, stream>>>(points, outputs, partials);

    const double scale = 0.01 / ((double)n * (double)(n - 1));
    cont_final<<<1, 1024, 0, stream>>>(partials, NBLOCKS, out, scale);
}